// Round 3
// baseline (299.188 us; speedup 1.0000x reference)
//
#include <hip/hip_runtime.h>
#include <stdint.h>

typedef float v4f __attribute__((ext_vector_type(4)));

// Factored algorithm (unchanged from R2):
//   pre[e,o] = hs.(W1a[o]+W2[o]) + hd.(W1b[o]+W2[o]) + bond[e]*W1c[o] + (b1+b2)[o]
//   node tables: A = atom @ U^T, B = atom @ V^T   (N=10k << E=320k)
//   edge pass:   out[e] = leaky(A[src[e]] + B[dst[e]] + bond[e]*c + bias)

// ---------------------------------------------------------------------------
// prep: fused weights.
//   Wf[256][128]: row o: U[o][k]=W1[o,k]+W2[o,k]; row 128+o: V[o][k]=W1[o,128+k]+W2[o,k]
//   cb[0:128]=c (W1[:,256]); cb[128:256]=b1+b2
// ---------------------------------------------------------------------------
__global__ __launch_bounds__(256) void prep_kernel(
    const float* __restrict__ W1, const float* __restrict__ b1,
    const float* __restrict__ W2, const float* __restrict__ b2,
    float* __restrict__ Wf, float* __restrict__ cb)
{
    int idx = blockIdx.x * 256 + threadIdx.x;
    if (idx < 32768) {
        int r = idx >> 7, k = idx & 127;
        float w2 = W2[(r & 127) * 128 + k];
        float w1 = (r < 128) ? W1[r * 257 + k]
                             : W1[(r - 128) * 257 + 128 + k];
        Wf[idx] = w1 + w2;
    }
    if (idx < 128) {
        cb[idx]       = W1[idx * 257 + 256];
        cb[128 + idx] = b1[idx] + b2[idx];
    }
}

// ---------------------------------------------------------------------------
// node transform, 4x4 register-tiled:
// block = 16 nodes x 256 output cols (col<128 -> A table, col>=128 -> B).
// 256 threads = 64 col-groups x 4 node-groups. Thread (c,g) owns cols
// {c, c+64, c+128, c+192} and nodes {4g..4g+3}: per k-chunk 8 b128 loads
// feed 64 FMAs (vs 4 FMA/load in the untiled version -> ~2x fewer VMEM ops).
// ---------------------------------------------------------------------------
__global__ __launch_bounds__(256) void node_kernel(
    const float* __restrict__ atom, const float* __restrict__ Wf,
    float* __restrict__ A, float* __restrict__ B, int N)
{
    const int t = threadIdx.x;
    const int c = t & 63;
    const int g = t >> 6;
    const int nbase = blockIdx.x * 16 + g * 4;

    const float4* __restrict__ w0 = (const float4*)(Wf + (size_t)(c      ) * 128);
    const float4* __restrict__ w1 = (const float4*)(Wf + (size_t)(c +  64) * 128);
    const float4* __restrict__ w2 = (const float4*)(Wf + (size_t)(c + 128) * 128);
    const float4* __restrict__ w3 = (const float4*)(Wf + (size_t)(c + 192) * 128);

    int r0 = nbase + 0; if (r0 >= N) r0 = N - 1;  // clamp: duplicate work, store guarded
    int r1 = nbase + 1; if (r1 >= N) r1 = N - 1;
    int r2 = nbase + 2; if (r2 >= N) r2 = N - 1;
    int r3 = nbase + 3; if (r3 >= N) r3 = N - 1;
    const float4* __restrict__ a0 = (const float4*)(atom + (size_t)r0 * 128);
    const float4* __restrict__ a1 = (const float4*)(atom + (size_t)r1 * 128);
    const float4* __restrict__ a2 = (const float4*)(atom + (size_t)r2 * 128);
    const float4* __restrict__ a3 = (const float4*)(atom + (size_t)r3 * 128);

    float acc[4][4];
#pragma unroll
    for (int j = 0; j < 4; ++j)
#pragma unroll
        for (int i = 0; i < 4; ++i) acc[j][i] = 0.f;

#pragma unroll 4
    for (int kc = 0; kc < 32; ++kc) {
        float4 w[4] = { w0[kc], w1[kc], w2[kc], w3[kc] };
        float4 a[4] = { a0[kc], a1[kc], a2[kc], a3[kc] };
#pragma unroll
        for (int j = 0; j < 4; ++j)
#pragma unroll
            for (int i = 0; i < 4; ++i)
                acc[j][i] += w[j].x * a[i].x + w[j].y * a[i].y
                           + w[j].z * a[i].z + w[j].w * a[i].w;
    }

#pragma unroll
    for (int j = 0; j < 4; ++j) {
        const int col = c + 64 * j;
        float* __restrict__ outp = (col < 128) ? A : B;
        const int o = col & 127;
#pragma unroll
        for (int i = 0; i < 4; ++i) {
            const int row = nbase + i;
            if (row < N) outp[(size_t)row * 128 + o] = acc[j][i];
        }
    }
}

// ---------------------------------------------------------------------------
// edge pass: out[e,:] = leaky(A[src[e]] + B[dst[e]] + bond[e]*c + bias)
// 32 lanes/edge, 8 edges/block. Nontemporal output stores (write-once) keep
// the 10.2 MB A/B gather tables resident in L2 instead of being evicted by
// 164 MB of streaming writes; src/dst/bond are streamed nontemporal too.
// ---------------------------------------------------------------------------
__global__ __launch_bounds__(256) void edge_kernel(
    const int* __restrict__ src, const int* __restrict__ dst,
    const float* __restrict__ bond,
    const float* __restrict__ A, const float* __restrict__ B,
    const float* __restrict__ cb, v4f* __restrict__ out, int E)
{
    const int g = threadIdx.x >> 5;
    const int l = threadIdx.x & 31;
    const int e = blockIdx.x * 8 + g;
    if (e >= E) return;

    const int s   = __builtin_nontemporal_load(src + e);
    const int d   = __builtin_nontemporal_load(dst + e);
    const float bv = __builtin_nontemporal_load(bond + e);

    float4 a  = ((const float4*)A)[(size_t)s * 32 + l];
    float4 b  = ((const float4*)B)[(size_t)d * 32 + l];
    float4 c  = ((const float4*)cb)[l];
    float4 bi = ((const float4*)cb)[32 + l];

    v4f x;
    x.x = a.x + b.x + bv * c.x + bi.x;
    x.y = a.y + b.y + bv * c.y + bi.y;
    x.z = a.z + b.z + bv * c.z + bi.z;
    x.w = a.w + b.w + bv * c.w + bi.w;
    x.x = x.x > 0.f ? x.x : 0.01f * x.x;
    x.y = x.y > 0.f ? x.y : 0.01f * x.y;
    x.z = x.z > 0.f ? x.z : 0.01f * x.z;
    x.w = x.w > 0.f ? x.w : 0.01f * x.w;

    __builtin_nontemporal_store(x, out + (size_t)e * 32 + l);
}

// ---------------------------------------------------------------------------
extern "C" void kernel_launch(void* const* d_in, const int* in_sizes, int n_in,
                              void* d_out, int out_size, void* d_ws, size_t ws_size,
                              hipStream_t stream)
{
    const float* atom = (const float*)d_in[0];  // [N,128] fp32
    const float* bond = (const float*)d_in[1];  // [E,1]  fp32
    const int*   src  = (const int*)d_in[2];    // [E]
    const int*   dst  = (const int*)d_in[3];    // [E]
    const float* W1   = (const float*)d_in[4];  // [128,257] fp32
    const float* b1   = (const float*)d_in[5];  // [128]
    const float* W2   = (const float*)d_in[6];  // [128,128] fp32
    const float* b2   = (const float*)d_in[7];  // [128]

    const int N = in_sizes[0] / 128;
    const int E = in_sizes[2];

    // workspace (fp32): Wf[256*128] | cb[256] | A[N*128] | B[N*128]  (~10.4 MB)
    float* Wf = (float*)d_ws;
    float* cb = Wf + 32768;
    float* A  = cb + 256;
    float* B  = A + (size_t)N * 128;

    prep_kernel<<<128, 256, 0, stream>>>(W1, b1, W2, b2, Wf, cb);
    node_kernel<<<(N + 15) / 16, 256, 0, stream>>>(atom, Wf, A, B, N);
    edge_kernel<<<(E + 7) / 8, 256, 0, stream>>>(src, dst, bond, A, B, cb,
                                                 (v4f*)d_out, E);
}

// Round 4
// 266.869 us; speedup vs baseline: 1.1211x; 1.1211x over previous
//
#include <hip/hip_runtime.h>
#include <stdint.h>

// Factored algorithm:
//   pre[e,o] = hs.(W1a[o]+W2[o]) + hd.(W1b[o]+W2[o]) + bond[e]*W1c[o] + (b1+b2)[o]
//   node tables: A = atom @ U^T, B = atom @ V^T   (N=10k << E=320k)
//   edge pass:   out[e] = leaky(A[src[e]] + B[dst[e]] + bond[e]*c + bias)
// R4: A/B tables stored bf16-packed (5.1 MB total -> L2-resident gathers,
//     half the gather bytes). Output stays fp32. nt stores reverted (R3 regression).

__device__ __forceinline__ float bflo(uint32_t u) { return __uint_as_float(u << 16); }
__device__ __forceinline__ float bfhi(uint32_t u) { return __uint_as_float(u & 0xffff0000u); }
__device__ __forceinline__ uint32_t f2bf(float f) {           // RNE to bf16 bits
    uint32_t u = __float_as_uint(f);
    return (u + 0x7fffu + ((u >> 16) & 1u)) >> 16;
}

// ---------------------------------------------------------------------------
// prep: fused weights (fp32).
//   Wf[256][128]: row o: U[o][k]=W1[o,k]+W2[o,k]; row 128+o: V[o][k]=W1[o,128+k]+W2[o,k]
//   cb[0:128]=c (W1[:,256]); cb[128:256]=b1+b2
// ---------------------------------------------------------------------------
__global__ __launch_bounds__(256) void prep_kernel(
    const float* __restrict__ W1, const float* __restrict__ b1,
    const float* __restrict__ W2, const float* __restrict__ b2,
    float* __restrict__ Wf, float* __restrict__ cb)
{
    int idx = blockIdx.x * 256 + threadIdx.x;
    if (idx < 32768) {
        int r = idx >> 7, k = idx & 127;
        float w2 = W2[(r & 127) * 128 + k];
        float w1 = (r < 128) ? W1[r * 257 + k]
                             : W1[(r - 128) * 257 + 128 + k];
        Wf[idx] = w1 + w2;
    }
    if (idx < 128) {
        cb[idx]       = W1[idx * 257 + 256];
        cb[128 + idx] = b1[idx] + b2[idx];
    }
}

// ---------------------------------------------------------------------------
// node transform -> bf16-packed tables.
// Thread t: weight-row pair p = t&127 (rows {2p,2p+1}; p<64 -> A cols {2p,2p+1},
// p>=64 -> B cols {2p-128,...}), node-half nh = t>>7 (8 nodes).
// Per k-chunk: 10 b128 loads feed 128 FMAs; store packs 2 bf16 per u32.
// ---------------------------------------------------------------------------
__global__ __launch_bounds__(256) void node_kernel(
    const float* __restrict__ atom, const float* __restrict__ Wf,
    uint32_t* __restrict__ Abf, uint32_t* __restrict__ Bbf, int N)
{
    const int t = threadIdx.x;
    const int p  = t & 127;
    const int nh = t >> 7;
    const int base = blockIdx.x * 16 + nh * 8;
    if (base >= N) return;

    const float4* __restrict__ w0 = (const float4*)(Wf + (size_t)(2 * p    ) * 128);
    const float4* __restrict__ w1 = (const float4*)(Wf + (size_t)(2 * p + 1) * 128);

    const float4* ar[8];
#pragma unroll
    for (int i = 0; i < 8; ++i) {
        int row = base + i;
        if (row >= N) row = N - 1;   // clamp: duplicate work, store guarded
        ar[i] = (const float4*)(atom + (size_t)row * 128);
    }

    float acc0[8], acc1[8];
#pragma unroll
    for (int i = 0; i < 8; ++i) { acc0[i] = 0.f; acc1[i] = 0.f; }

#pragma unroll 4
    for (int kc = 0; kc < 32; ++kc) {
        float4 wa = w0[kc];
        float4 wb = w1[kc];
#pragma unroll
        for (int i = 0; i < 8; ++i) {
            float4 a = ar[i][kc];
            acc0[i] += wa.x * a.x + wa.y * a.y + wa.z * a.z + wa.w * a.w;
            acc1[i] += wb.x * a.x + wb.y * a.y + wb.z * a.z + wb.w * a.w;
        }
    }

    uint32_t* __restrict__ outp = (p < 64) ? Abf : Bbf;
    const int pi = p & 63;            // u32 column index within 64-u32 row
#pragma unroll
    for (int i = 0; i < 8; ++i) {
        const int row = base + i;
        if (row < N)
            outp[(size_t)row * 64 + pi] = f2bf(acc0[i]) | (f2bf(acc1[i]) << 16);
    }
}

// ---------------------------------------------------------------------------
// edge pass: out[e,:] = leaky(A[src[e]] + B[dst[e]] + bond[e]*c + bias)
// 32 lanes/edge, 8 edges/block. Lane l covers cols 4l..4l+3: one uint2
// (4 bf16) per table, fp32 c/bias, 16 B fp32 store (512 B/edge contiguous).
// ---------------------------------------------------------------------------
__global__ __launch_bounds__(256) void edge_kernel(
    const int* __restrict__ src, const int* __restrict__ dst,
    const float* __restrict__ bond,
    const uint2* __restrict__ Abf, const uint2* __restrict__ Bbf,
    const float* __restrict__ cb, float4* __restrict__ out, int E)
{
    const int g = threadIdx.x >> 5;
    const int l = threadIdx.x & 31;
    const int e = blockIdx.x * 8 + g;
    if (e >= E) return;

    const int s = src[e];
    const int d = dst[e];
    const float bv = bond[e];

    uint2 ua = Abf[(size_t)s * 32 + l];
    uint2 ub = Bbf[(size_t)d * 32 + l];
    float4 c  = ((const float4*)cb)[l];
    float4 bi = ((const float4*)cb)[32 + l];

    float4 x;
    x.x = bflo(ua.x) + bflo(ub.x) + bv * c.x + bi.x;
    x.y = bfhi(ua.x) + bfhi(ub.x) + bv * c.y + bi.y;
    x.z = bflo(ua.y) + bflo(ub.y) + bv * c.z + bi.z;
    x.w = bfhi(ua.y) + bfhi(ub.y) + bv * c.w + bi.w;
    x.x = x.x > 0.f ? x.x : 0.01f * x.x;
    x.y = x.y > 0.f ? x.y : 0.01f * x.y;
    x.z = x.z > 0.f ? x.z : 0.01f * x.z;
    x.w = x.w > 0.f ? x.w : 0.01f * x.w;

    out[(size_t)e * 32 + l] = x;
}

// ---------------------------------------------------------------------------
extern "C" void kernel_launch(void* const* d_in, const int* in_sizes, int n_in,
                              void* d_out, int out_size, void* d_ws, size_t ws_size,
                              hipStream_t stream)
{
    const float* atom = (const float*)d_in[0];  // [N,128] fp32
    const float* bond = (const float*)d_in[1];  // [E,1]  fp32
    const int*   src  = (const int*)d_in[2];    // [E]
    const int*   dst  = (const int*)d_in[3];    // [E]
    const float* W1   = (const float*)d_in[4];  // [128,257] fp32
    const float* b1   = (const float*)d_in[5];  // [128]
    const float* W2   = (const float*)d_in[6];  // [128,128] fp32
    const float* b2   = (const float*)d_in[7];  // [128]

    const int N = in_sizes[0] / 128;
    const int E = in_sizes[2];

    // workspace: Wf[32768]f | cb[256]f | Abf[N*64]u32 | Bbf[N*64]u32  (~5.3 MB)
    float*    Wf  = (float*)d_ws;
    float*    cb  = Wf + 32768;
    uint32_t* Abf = (uint32_t*)(cb + 256);
    uint32_t* Bbf = Abf + (size_t)N * 64;

    prep_kernel<<<128, 256, 0, stream>>>(W1, b1, W2, b2, Wf, cb);
    node_kernel<<<(N + 15) / 16, 256, 0, stream>>>(atom, Wf, Abf, Bbf, N);
    edge_kernel<<<(E + 7) / 8, 256, 0, stream>>>(src, dst, bond,
                                                 (const uint2*)Abf, (const uint2*)Bbf,
                                                 cb, (float4*)d_out, E);
}